// Round 5
// baseline (169.898 us; speedup 1.0000x reference)
//
#include <hip/hip_runtime.h>

typedef unsigned short u16;
typedef short s16x8 __attribute__((ext_vector_type(8)));
typedef float f32x4 __attribute__((ext_vector_type(4)));

// ---------- scalar dtype helpers ----------
__device__ __forceinline__ u16 f2bf(float f) {
    union { float f; unsigned u; } v; v.f = f;
    unsigned r = v.u + 0x7FFFu + ((v.u >> 16) & 1u);   // RNE
    return (u16)(r >> 16);
}
__device__ __forceinline__ float bf2f(u16 h) {
    union { unsigned u; float f; } v; v.u = ((unsigned)h) << 16;
    return v.f;
}
__device__ __forceinline__ u16 f2h(float f) {
    _Float16 h = (_Float16)f;
    union { _Float16 h; u16 u; } v; v.h = h; return v.u;
}
__device__ __forceinline__ float h2f(u16 u) {
    union { u16 u; _Float16 h; } v; v.u = u; return (float)v.h;
}

// async global->LDS, 16B per lane; LDS dest = wave-uniform base + lane*16
__device__ __forceinline__ void gl_lds16(const u16* g, u16* l) {
    __builtin_amdgcn_global_load_lds(
        (const __attribute__((address_space(1))) void*)g,
        (__attribute__((address_space(3))) void*)l,
        16, 0, 0);
}

// ---------- fp32 -> bf16 convert ----------
__global__ __launch_bounds__(256) void f32_to_bf16(const float* __restrict__ in,
                                                   u16* __restrict__ out, int n) {
    int i = (blockIdx.x * 256 + threadIdx.x) * 4;
    int stride = gridDim.x * 256 * 4;
    for (; i < n; i += stride) {
        float4 v = *reinterpret_cast<const float4*>(in + i);
        ushort4 o;
        o.x = f2bf(v.x); o.y = f2bf(v.y); o.z = f2bf(v.z); o.w = f2bf(v.w);
        *reinterpret_cast<ushort4*>(out + i) = o;
    }
}

template <typename CT>
__device__ __forceinline__ void store_c(CT* p, float v) {
    if constexpr (__is_same(CT, u16))            *p = f2bf(v);
    else if constexpr (__is_same(CT, _Float16))  *p = (_Float16)v;
    else                                         *p = v;
}

// swizzled LDS fragment read: base in u16, row in [0,128), kk in {0,1}, fq in [0,4)
__device__ __forceinline__ s16x8 ldfrag(const u16* base, int row, int kk, int fq) {
    int cb = ((kk << 6) + (fq << 4)) ^ ((row & 7) << 4);   // byte col, XOR bits 4-6
    return *reinterpret_cast<const s16x8*>(base + row * 64 + (cb >> 1));
}

// ---------- bf16 GEMM, C = A @ B^T ----------
// 128x128 tile, 8 waves (512 thr), wave tile 64x32, BK=64, double-buffered LDS
// (64KB -> 2 blocks/CU -> 4 waves/SIMD), counted vmcnt, raw barriers, XOR-swizzle.
// MODE 0: plain. MODE 1: causal tile skip. MODE 2: PV per-row-tile K limit,
// longest-first, grid (N/128, 16*4): y decodes (batch=y&3, rowtile=15-(y>>2)).
template <int MODE, typename CT>
__global__ __launch_bounds__(512)
void gemm_bt(const u16* __restrict__ A, const u16* __restrict__ B, CT* __restrict__ C,
             int K, int lda, int ldb, int ldc, long sA, long sB, long sC) {
    int bx = blockIdx.x, by = blockIdx.y, bz = blockIdx.z;
    if (MODE == 1 && bx > by) return;
    if (MODE == 2) { bz = blockIdx.y & 3; by = 15 - (int)(blockIdx.y >> 2); }
    A += (size_t)bz * sA; B += (size_t)bz * sB; C += (size_t)bz * sC;
    int kend = K;
    if (MODE == 2) { int kl = (by + 1) * 128; kend = kl < K ? kl : K; }
    const int NT = kend >> 6;   // K-tiles of 64

    __shared__ u16 lds[32768];  // [2 bufs][ A 8192 u16 | B 8192 u16 ]

    const int tid  = threadIdx.x;
    const int lane = tid & 63;
    const int wave = tid >> 6;          // 0..7
    const int wr = (wave >> 2) * 64;    // wave row offset (0 or 64)
    const int wc = (wave & 3) * 32;     // wave col offset (0/32/64/96)
    const int fr = lane & 15;
    const int fq = lane >> 4;
    const int tm = by * 128, tn = bx * 128;

    // --- staging: 4 x 16B per thread per K-tile (2 A + 2 B) ---
    // LDS dest (linear): j*8192B + tid*16B -> row = j*64 + tid/8, byte col = (tid&7)*16
    // global source col pre-swizzled (rule #21 both-sides)
    const int srow = tid >> 3;                                  // 0..63
    const int gco  = (((tid & 7) ^ (srow & 7)) << 3);           // u16 col
    const u16* aR[2]; const u16* bR[2];
#pragma unroll
    for (int j = 0; j < 2; ++j) {
        aR[j] = A + (size_t)(tm + j * 64 + srow) * lda + gco;
        bR[j] = B + (size_t)(tn + j * 64 + srow) * ldb + gco;
    }

#define STAGE(b2, k0) do {                                                        \
    _Pragma("unroll") for (int j = 0; j < 2; ++j)                                 \
        gl_lds16(aR[j] + (k0), lds + (b2) * 16384 + j * 4096 + wave * 512);       \
    _Pragma("unroll") for (int j = 0; j < 2; ++j)                                 \
        gl_lds16(bR[j] + (k0), lds + (b2) * 16384 + 8192 + j * 4096 + wave * 512);\
  } while (0)

    f32x4 acc[4][2];
#pragma unroll
    for (int m = 0; m < 4; ++m)
#pragma unroll
        for (int n = 0; n < 2; ++n) acc[m][n] = {0.f, 0.f, 0.f, 0.f};

    STAGE(0, 0);
    if (NT > 1) STAGE(1, 64);

    for (int t = 0; t < NT; ++t) {
        const int buf = t & 1;
        if (t + 1 < NT) { asm volatile("s_waitcnt vmcnt(4)" ::: "memory"); }
        else            { asm volatile("s_waitcnt vmcnt(0)" ::: "memory"); }
        __builtin_amdgcn_s_barrier();
        __builtin_amdgcn_sched_barrier(0);

        const u16* Ab = lds + buf * 16384;
        const u16* Bb = Ab + 8192;
        s16x8 bf0[2], bf1[2];
#pragma unroll
        for (int n = 0; n < 2; ++n) {
            bf0[n] = ldfrag(Bb, wc + n * 16 + fr, 0, fq);
            bf1[n] = ldfrag(Bb, wc + n * 16 + fr, 1, fq);
        }
        __builtin_amdgcn_s_setprio(1);
#pragma unroll
        for (int m = 0; m < 4; ++m) {
            s16x8 a0 = ldfrag(Ab, wr + m * 16 + fr, 0, fq);
            s16x8 a1 = ldfrag(Ab, wr + m * 16 + fr, 1, fq);
#pragma unroll
            for (int n = 0; n < 2; ++n) {
                acc[m][n] = __builtin_amdgcn_mfma_f32_16x16x32_bf16(a0, bf0[n], acc[m][n], 0, 0, 0);
                acc[m][n] = __builtin_amdgcn_mfma_f32_16x16x32_bf16(a1, bf1[n], acc[m][n], 0, 0, 0);
            }
        }
        __builtin_amdgcn_s_setprio(0);
        __builtin_amdgcn_sched_barrier(0);
        __builtin_amdgcn_s_barrier();           // all waves done reading buf
        if (t + 2 < NT) STAGE(buf, (t + 2) << 6);
    }
#undef STAGE

    // epilogue: D row=(lane>>4)*4+r, col=lane&15 (m89-verified)
#pragma unroll
    for (int m = 0; m < 4; ++m)
#pragma unroll
        for (int n = 0; n < 2; ++n)
#pragma unroll
            for (int r = 0; r < 4; ++r) {
                int row = tm + wr + m * 16 + fq * 4 + r;
                int col = tn + wc + n * 16 + fr;
                store_c(&C[(size_t)row * ldc + col], acc[m][n][r]);
            }
}

// ---------- trig table: trig[t][d] = cos, trig[t][512+d] = sin (fp16) ----------
__global__ __launch_bounds__(256)
void trig_table(u16* __restrict__ trig) {
    const int t = blockIdx.x;
    const float L = 0.025952563241307517f;  // log2(10000)/512
    u16* row = trig + (size_t)t * 1024;
#pragma unroll
    for (int i = 0; i < 2; ++i) {
        int d = threadIdx.x + i * 256;
        float invf = exp2f(-(float)d * L);
        float ang = (float)t * invf;
        float s, c;
        sincosf(ang, &s, &c);
        row[d] = f2h(c);
        row[512 + d] = f2h(s);
    }
}

// ---------- RoPE + L2 norm * sqk*32, in-place on Q,K ----------
__global__ __launch_bounds__(256)
void rope_norm(u16* __restrict__ qkv, const float* __restrict__ sqk,
               const u16* __restrict__ trig) {
    const int row = blockIdx.x;        // b*2048 + t
    const int t = row & 2047;
    u16* qp = qkv + (size_t)row * 3072;
    u16* kp = qp + 1024;
    const u16* tb = trig + (size_t)t * 1024;

    float q0v[2], q1v[2], k0v[2], k1v[2];
    float ssq_q = 0.f, ssq_k = 0.f;

#pragma unroll
    for (int i = 0; i < 2; ++i) {
        int d = threadIdx.x + i * 256;           // 0..511
        float c = h2f(tb[d]);
        float s = h2f(tb[512 + d]);
        float q0 = bf2f(qp[d]), q1 = bf2f(qp[d + 512]);
        float k0 = bf2f(kp[d]), k1 = bf2f(kp[d + 512]);
        float nq0 = q0 * c - q1 * s;
        float nq1 = q1 * c + q0 * s;
        float nk0 = k0 * c - k1 * s;
        float nk1 = k1 * c + k0 * s;
        q0v[i] = nq0; q1v[i] = nq1; k0v[i] = nk0; k1v[i] = nk1;
        ssq_q += nq0 * nq0 + nq1 * nq1;
        ssq_k += nk0 * nk0 + nk1 * nk1;
    }

#pragma unroll
    for (int off = 32; off; off >>= 1) {
        ssq_q += __shfl_xor(ssq_q, off);
        ssq_k += __shfl_xor(ssq_k, off);
    }
    __shared__ float red[8];
    int wave = threadIdx.x >> 6, lane = threadIdx.x & 63;
    if (lane == 0) { red[wave] = ssq_q; red[4 + wave] = ssq_k; }
    __syncthreads();
    float rq = rsqrtf(red[0] + red[1] + red[2] + red[3]);
    float rk = rsqrtf(red[4] + red[5] + red[6] + red[7]);

#pragma unroll
    for (int i = 0; i < 2; ++i) {
        int d = threadIdx.x + i * 256;
        float s0 = sqk[d] * 32.f, s1 = sqk[d + 512] * 32.f;
        qp[d]       = f2bf(q0v[i] * rq * s0);
        qp[d + 512] = f2bf(q1v[i] * rq * s1);
        kp[d]       = f2bf(k0v[i] * rk * s0);
        kp[d + 512] = f2bf(k1v[i] * rk * s1);
    }
}

// ---------- V transpose: VT[b][n][k] = qkv[(b*2048+k)][2048+n] ----------
__global__ __launch_bounds__(256)
void transpose_v(const u16* __restrict__ qkv, u16* __restrict__ VT) {
    __shared__ u16 tile[32][33];
    int b = blockIdx.z;
    int n0 = blockIdx.x * 32;
    int k0 = blockIdx.y * 32;
    int tx = threadIdx.x, ty = threadIdx.y;
    const u16* src = qkv + (size_t)b * 2048 * 3072 + 2048;
#pragma unroll
    for (int i = 0; i < 4; ++i)
        tile[ty + i * 8][tx] = src[(size_t)(k0 + ty + i * 8) * 3072 + n0 + tx];
    __syncthreads();
    u16* dst = VT + (size_t)b * 1024 * 2048;
#pragma unroll
    for (int i = 0; i < 4; ++i)
        dst[(size_t)(n0 + ty + i * 8) * 2048 + k0 + tx] = tile[tx][ty + i * 8];
}

// ---------- in-place causal softmax over fp16 S rows -> bf16 P (same bytes) ----------
// Only cols [0, ((r>>7)+1)*128) are touched — exactly what PV reads.
__global__ __launch_bounds__(256)
void softmax_inplace(u16* __restrict__ Sbase) {
    const int r = blockIdx.x;
    const int b = blockIdx.y;
    u16* row = Sbase + (size_t)b * 4194304 + (size_t)r * 2048;
    const int n = r + 1;
    const int kcap = ((r >> 7) + 1) << 7;
    const int tid = threadIdx.x;
    const bool act = (tid * 8) < kcap;

    union { uint4 u; u16 h[8]; } U;
    if (act) U.u = *reinterpret_cast<const uint4*>(row + tid * 8);
    float v[8];
    float m = -1e30f;
#pragma unroll
    for (int i = 0; i < 8; ++i) {
        int c = tid * 8 + i;
        v[i] = (act && c < n) ? h2f(U.h[i]) : -1e30f;
        m = fmaxf(m, v[i]);
    }
#pragma unroll
    for (int off = 32; off; off >>= 1) m = fmaxf(m, __shfl_xor(m, off));
    __shared__ float redm[4], redsum[4];
    int wave = tid >> 6, lane = tid & 63;
    if (lane == 0) redm[wave] = m;
    __syncthreads();
    m = fmaxf(fmaxf(redm[0], redm[1]), fmaxf(redm[2], redm[3]));
    float M = 32.f * m;

    float sum = 0.f;
#pragma unroll
    for (int i = 0; i < 8; ++i) {
        int c = tid * 8 + i;
        float e = (v[i] > -1e29f) ? __expf(32.f * v[i] - M) : 0.f;
        if (c >= n) e = 0.f;
        v[i] = e;
        sum += e;
    }
#pragma unroll
    for (int off = 32; off; off >>= 1) sum += __shfl_xor(sum, off);
    if (lane == 0) redsum[wave] = sum;
    __syncthreads();
    sum = redsum[0] + redsum[1] + redsum[2] + redsum[3];
    float inv = 1.f / sum;

    if (act) {
        union { uint4 u; u16 h[8]; } O;
#pragma unroll
        for (int i = 0; i < 8; ++i) O.h[i] = f2bf(v[i] * inv);
        *reinterpret_cast<uint4*>(row + tid * 8) = O.u;
    }
}

// ---------- host launcher ----------
extern "C" void kernel_launch(void* const* d_in, const int* in_sizes, int n_in,
                              void* d_out, int out_size, void* d_ws, size_t ws_size,
                              hipStream_t stream) {
    const float* x   = (const float*)d_in[0];   // [4,2048,1024]
    const float* w   = (const float*)d_in[1];   // [3072,1024]
    const float* sqk = (const float*)d_in[2];   // [1024]
    float* out = (float*)d_out;

    const size_t SZ_XB  = (size_t)8192 * 1024 * 2;        // aliased by VT later
    const size_t SZ_WB  = (size_t)3072 * 1024 * 2;
    const size_t SZ_QKV = (size_t)8192 * 3072 * 2;
    const size_t SZ_S   = (size_t)4 * 2048 * 2048 * 2;    // fp16, 4 slots
    const size_t SZ_TR  = (size_t)2048 * 1024 * 2;
    if (ws_size < SZ_XB + SZ_WB + SZ_QKV + SZ_S + SZ_TR) return;

    char* ws = (char*)d_ws;
    u16* xb   = (u16*)ws;  ws += SZ_XB;
    u16* wb   = (u16*)ws;  ws += SZ_WB;
    u16* qkv  = (u16*)ws;  ws += SZ_QKV;
    u16* S    = (u16*)ws;  ws += SZ_S;
    u16* trig = (u16*)ws;
    u16* VT   = xb;   // alias: xb dead after QKV GEMM

    f32_to_bf16<<<2048, 256, 0, stream>>>(x, xb, 8192 * 1024);
    f32_to_bf16<<<768, 256, 0, stream>>>(w, wb, 3072 * 1024);

    // qkv = x @ W^T : [8192,3072], 1536 blocks (3 clean rounds @ 2/CU)
    gemm_bt<0, u16><<<dim3(24, 64, 1), 512, 0, stream>>>(
        xb, wb, qkv, 1024, 1024, 1024, 3072, 0, 0, 0);

    trig_table<<<2048, 256, 0, stream>>>(trig);
    rope_norm<<<8192, 256, 0, stream>>>(qkv, sqk, trig);

    transpose_v<<<dim3(32, 64, 4), dim3(32, 8), 0, stream>>>(qkv, VT);

    // S = Q @ K^T, all 4 batches, causal tiles, fp16 output
    gemm_bt<1, _Float16><<<dim3(16, 16, 4), 512, 0, stream>>>(
        qkv, qkv + 1024, (_Float16*)S, 1024, 3072, 3072, 2048,
        (long)2048 * 3072, (long)2048 * 3072, (long)2048 * 2048);

    softmax_inplace<<<dim3(2048, 4), 256, 0, stream>>>(S);

    // out = P @ V, longest-first over row tiles, grid (8, 64)
    gemm_bt<2, float><<<dim3(8, 64, 1), 512, 0, stream>>>(
        S, VT, out, 2048, 2048, 2048, 1024,
        (long)2048 * 2048, (long)1024 * 2048, (long)2048 * 1024);
}

// Round 6
// 167.359 us; speedup vs baseline: 1.0152x; 1.0152x over previous
//
#include <hip/hip_runtime.h>

typedef unsigned short u16;
typedef short s16x8 __attribute__((ext_vector_type(8)));
typedef float f32x4 __attribute__((ext_vector_type(4)));

// ---------- scalar dtype helpers ----------
__device__ __forceinline__ u16 f2bf(float f) {
    union { float f; unsigned u; } v; v.f = f;
    unsigned r = v.u + 0x7FFFu + ((v.u >> 16) & 1u);   // RNE
    return (u16)(r >> 16);
}
__device__ __forceinline__ float bf2f(u16 h) {
    union { unsigned u; float f; } v; v.u = ((unsigned)h) << 16;
    return v.f;
}
__device__ __forceinline__ u16 f2h(float f) {
    _Float16 h = (_Float16)f;
    union { _Float16 h; u16 u; } v; v.h = h; return v.u;
}
__device__ __forceinline__ float h2f(u16 u) {
    union { u16 u; _Float16 h; } v; v.u = u; return (float)v.h;
}

// async global->LDS, 16B per lane; LDS dest = wave-uniform base + lane*16
__device__ __forceinline__ void gl_lds16(const u16* g, u16* l) {
    __builtin_amdgcn_global_load_lds(
        (const __attribute__((address_space(1))) void*)g,
        (__attribute__((address_space(3))) void*)l,
        16, 0, 0);
}

// ---------- fp32 -> bf16 convert ----------
__global__ __launch_bounds__(256) void f32_to_bf16(const float* __restrict__ in,
                                                   u16* __restrict__ out, int n) {
    int i = (blockIdx.x * 256 + threadIdx.x) * 4;
    int stride = gridDim.x * 256 * 4;
    for (; i < n; i += stride) {
        float4 v = *reinterpret_cast<const float4*>(in + i);
        ushort4 o;
        o.x = f2bf(v.x); o.y = f2bf(v.y); o.z = f2bf(v.z); o.w = f2bf(v.w);
        *reinterpret_cast<ushort4*>(out + i) = o;
    }
}

template <typename CT>
__device__ __forceinline__ void store_c(CT* p, float v) {
    if constexpr (__is_same(CT, u16))            *p = f2bf(v);
    else if constexpr (__is_same(CT, _Float16))  *p = (_Float16)v;
    else                                         *p = v;
}

// swizzled LDS fragment read: base in u16, row in [0,128), kk in {0,1}, fq in [0,4)
__device__ __forceinline__ s16x8 ldfrag(const u16* base, int row, int kk, int fq) {
    int cb = ((kk << 6) + (fq << 4)) ^ ((row & 7) << 4);   // byte col, XOR bits 4-6
    return *reinterpret_cast<const s16x8*>(base + row * 64 + (cb >> 1));
}

// ---------- bf16 GEMM, C = A @ B^T ----------
// 128x128 tile, 8 waves (512 thr), wave tile 64x32, BK=64, double-buffered LDS
// (64KB -> 2 blocks/CU), counted vmcnt, raw barriers, XOR-swizzle.
// MODE 0: QKV (grid 1536 1D) with 2D XCD-chunked swizzle: each XCD owns an
//         8-row-tile A band (2MB, L2-resident) and walks B in 8-col regions
//         (2MB) -> staging hits local L2 instead of Infinity Cache.
// MODE 1: causal tile skip. MODE 2: PV per-row-tile K limit, longest-first,
//         grid (N/128, 16*4): y decodes (batch=y&3, rowtile=15-(y>>2)).
template <int MODE, typename CT>
__global__ __launch_bounds__(512)
void gemm_bt(const u16* __restrict__ A, const u16* __restrict__ B, CT* __restrict__ C,
             int K, int lda, int ldb, int ldc, long sA, long sB, long sC) {
    int bx = blockIdx.x, by = blockIdx.y, bz = blockIdx.z;
    if (MODE == 0) {
        // grid = 1536 blocks 1D; tiles 24 (bx) x 64 (by); HW: xcd = bid % 8
        int bid = blockIdx.x;
        int xcd = bid & 7, idx = bid >> 3;      // 192 blocks per XCD, in time order
        int r = idx >> 6, w = idx & 63;         // 3 regions of 8bx x 8by
        bx = r * 8 + (w & 7);
        by = xcd * 8 + (w >> 3);
        bz = 0;
    }
    if (MODE == 1 && bx > by) return;
    if (MODE == 2) { bz = blockIdx.y & 3; by = 15 - (int)(blockIdx.y >> 2); }
    A += (size_t)bz * sA; B += (size_t)bz * sB; C += (size_t)bz * sC;
    int kend = K;
    if (MODE == 2) { int kl = (by + 1) * 128; kend = kl < K ? kl : K; }
    const int NT = kend >> 6;   // K-tiles of 64

    __shared__ u16 lds[32768];  // [2 bufs][ A 8192 u16 | B 8192 u16 ]

    const int tid  = threadIdx.x;
    const int lane = tid & 63;
    const int wave = tid >> 6;          // 0..7
    const int wr = (wave >> 2) * 64;    // wave row offset (0 or 64)
    const int wc = (wave & 3) * 32;     // wave col offset (0/32/64/96)
    const int fr = lane & 15;
    const int fq = lane >> 4;
    const int tm = by * 128, tn = bx * 128;

    // --- staging: 4 x 16B per thread per K-tile (2 A + 2 B) ---
    const int srow = tid >> 3;                                  // 0..63
    const int gco  = (((tid & 7) ^ (srow & 7)) << 3);           // u16 col (pre-swizzled)
    const u16* aR[2]; const u16* bR[2];
#pragma unroll
    for (int j = 0; j < 2; ++j) {
        aR[j] = A + (size_t)(tm + j * 64 + srow) * lda + gco;
        bR[j] = B + (size_t)(tn + j * 64 + srow) * ldb + gco;
    }

#define STAGE(b2, k0) do {                                                        \
    _Pragma("unroll") for (int j = 0; j < 2; ++j)                                 \
        gl_lds16(aR[j] + (k0), lds + (b2) * 16384 + j * 4096 + wave * 512);       \
    _Pragma("unroll") for (int j = 0; j < 2; ++j)                                 \
        gl_lds16(bR[j] + (k0), lds + (b2) * 16384 + 8192 + j * 4096 + wave * 512);\
  } while (0)

    f32x4 acc[4][2];
#pragma unroll
    for (int m = 0; m < 4; ++m)
#pragma unroll
        for (int n = 0; n < 2; ++n) acc[m][n] = {0.f, 0.f, 0.f, 0.f};

    STAGE(0, 0);
    if (NT > 1) STAGE(1, 64);

    for (int t = 0; t < NT; ++t) {
        const int buf = t & 1;
        if (t + 1 < NT) { asm volatile("s_waitcnt vmcnt(4)" ::: "memory"); }
        else            { asm volatile("s_waitcnt vmcnt(0)" ::: "memory"); }
        __builtin_amdgcn_s_barrier();
        __builtin_amdgcn_sched_barrier(0);

        const u16* Ab = lds + buf * 16384;
        const u16* Bb = Ab + 8192;
        s16x8 bf0[2], bf1[2];
#pragma unroll
        for (int n = 0; n < 2; ++n) {
            bf0[n] = ldfrag(Bb, wc + n * 16 + fr, 0, fq);
            bf1[n] = ldfrag(Bb, wc + n * 16 + fr, 1, fq);
        }
        __builtin_amdgcn_s_setprio(1);
#pragma unroll
        for (int m = 0; m < 4; ++m) {
            s16x8 a0 = ldfrag(Ab, wr + m * 16 + fr, 0, fq);
            s16x8 a1 = ldfrag(Ab, wr + m * 16 + fr, 1, fq);
#pragma unroll
            for (int n = 0; n < 2; ++n) {
                acc[m][n] = __builtin_amdgcn_mfma_f32_16x16x32_bf16(a0, bf0[n], acc[m][n], 0, 0, 0);
                acc[m][n] = __builtin_amdgcn_mfma_f32_16x16x32_bf16(a1, bf1[n], acc[m][n], 0, 0, 0);
            }
        }
        __builtin_amdgcn_s_setprio(0);
        __builtin_amdgcn_sched_barrier(0);
        __builtin_amdgcn_s_barrier();           // all waves done reading buf
        if (t + 2 < NT) STAGE(buf, (t + 2) << 6);
    }
#undef STAGE

    // epilogue: D row=(lane>>4)*4+r, col=lane&15 (m89-verified)
#pragma unroll
    for (int m = 0; m < 4; ++m)
#pragma unroll
        for (int n = 0; n < 2; ++n)
#pragma unroll
            for (int r = 0; r < 4; ++r) {
                int row = tm + wr + m * 16 + fq * 4 + r;
                int col = tn + wc + n * 16 + fr;
                store_c(&C[(size_t)row * ldc + col], acc[m][n][r]);
            }
}

// ---------- trig table: trig[t][d] = cos, trig[t][512+d] = sin (fp16) ----------
__global__ __launch_bounds__(256)
void trig_table(u16* __restrict__ trig) {
    const int t = blockIdx.x;
    const float L = 0.025952563241307517f;  // log2(10000)/512
    u16* row = trig + (size_t)t * 1024;
#pragma unroll
    for (int i = 0; i < 2; ++i) {
        int d = threadIdx.x + i * 256;
        float invf = exp2f(-(float)d * L);
        float ang = (float)t * invf;
        float s, c;
        sincosf(ang, &s, &c);
        row[d] = f2h(c);
        row[512 + d] = f2h(s);
    }
}

// ---------- RoPE + L2 norm * sqk*32, in-place on Q,K (vectorized dword loads) ----------
__global__ __launch_bounds__(256)
void rope_norm(u16* __restrict__ qkv, const float* __restrict__ sqk,
               const u16* __restrict__ trig) {
    const int row = blockIdx.x;        // b*2048 + t
    const int t = row & 2047;
    u16* qp = qkv + (size_t)row * 3072;
    u16* kp = qp + 1024;
    const u16* tb = trig + (size_t)t * 1024;
    const int d = threadIdx.x << 1;    // 0,2,...,510 (each thread: d, d+1 and partners)

    union U2 { uint u; u16 h[2]; };
    U2 qc0, qc1, kc0, kc1, cc, ss;
    qc0.u = *reinterpret_cast<const uint*>(qp + d);
    qc1.u = *reinterpret_cast<const uint*>(qp + 512 + d);
    kc0.u = *reinterpret_cast<const uint*>(kp + d);
    kc1.u = *reinterpret_cast<const uint*>(kp + 512 + d);
    cc.u  = *reinterpret_cast<const uint*>(tb + d);
    ss.u  = *reinterpret_cast<const uint*>(tb + 512 + d);

    float nq0[2], nq1[2], nk0[2], nk1[2];
    float ssq_q = 0.f, ssq_k = 0.f;
#pragma unroll
    for (int j = 0; j < 2; ++j) {
        float c = h2f(cc.h[j]), s = h2f(ss.h[j]);
        float q0 = bf2f(qc0.h[j]), q1 = bf2f(qc1.h[j]);
        float k0 = bf2f(kc0.h[j]), k1 = bf2f(kc1.h[j]);
        nq0[j] = q0 * c - q1 * s;
        nq1[j] = q1 * c + q0 * s;
        nk0[j] = k0 * c - k1 * s;
        nk1[j] = k1 * c + k0 * s;
        ssq_q += nq0[j] * nq0[j] + nq1[j] * nq1[j];
        ssq_k += nk0[j] * nk0[j] + nk1[j] * nk1[j];
    }

#pragma unroll
    for (int off = 32; off; off >>= 1) {
        ssq_q += __shfl_xor(ssq_q, off);
        ssq_k += __shfl_xor(ssq_k, off);
    }
    __shared__ float red[8];
    int wave = threadIdx.x >> 6, lane = threadIdx.x & 63;
    if (lane == 0) { red[wave] = ssq_q; red[4 + wave] = ssq_k; }
    __syncthreads();
    float rq = rsqrtf(red[0] + red[1] + red[2] + red[3]);
    float rk = rsqrtf(red[4] + red[5] + red[6] + red[7]);

    float2 sq0 = *reinterpret_cast<const float2*>(sqk + d);
    float2 sq1 = *reinterpret_cast<const float2*>(sqk + 512 + d);
    float s0[2] = {sq0.x * 32.f, sq0.y * 32.f};
    float s1[2] = {sq1.x * 32.f, sq1.y * 32.f};

    U2 oq0, oq1, ok0, ok1;
#pragma unroll
    for (int j = 0; j < 2; ++j) {
        oq0.h[j] = f2bf(nq0[j] * rq * s0[j]);
        oq1.h[j] = f2bf(nq1[j] * rq * s1[j]);
        ok0.h[j] = f2bf(nk0[j] * rk * s0[j]);
        ok1.h[j] = f2bf(nk1[j] * rk * s1[j]);
    }
    *reinterpret_cast<uint*>(qp + d)       = oq0.u;
    *reinterpret_cast<uint*>(qp + 512 + d) = oq1.u;
    *reinterpret_cast<uint*>(kp + d)       = ok0.u;
    *reinterpret_cast<uint*>(kp + 512 + d) = ok1.u;
}

// ---------- V transpose: VT[b][n][k] = qkv[(b*2048+k)][2048+n] ----------
__global__ __launch_bounds__(256)
void transpose_v(const u16* __restrict__ qkv, u16* __restrict__ VT) {
    __shared__ u16 tile[32][33];
    int b = blockIdx.z;
    int n0 = blockIdx.x * 32;
    int k0 = blockIdx.y * 32;
    int tx = threadIdx.x, ty = threadIdx.y;
    const u16* src = qkv + (size_t)b * 2048 * 3072 + 2048;
#pragma unroll
    for (int i = 0; i < 4; ++i)
        tile[ty + i * 8][tx] = src[(size_t)(k0 + ty + i * 8) * 3072 + n0 + tx];
    __syncthreads();
    u16* dst = VT + (size_t)b * 1024 * 2048;
#pragma unroll
    for (int i = 0; i < 4; ++i)
        dst[(size_t)(n0 + ty + i * 8) * 2048 + k0 + tx] = tile[tx][ty + i * 8];
}

// ---------- in-place causal softmax over fp16 S rows -> bf16 P (same bytes) ----------
// Only cols [0, ((r>>7)+1)*128) are touched — exactly what PV reads.
__global__ __launch_bounds__(256)
void softmax_inplace(u16* __restrict__ Sbase) {
    const int r = blockIdx.x;
    const int b = blockIdx.y;
    u16* row = Sbase + (size_t)b * 4194304 + (size_t)r * 2048;
    const int n = r + 1;
    const int kcap = ((r >> 7) + 1) << 7;
    const int tid = threadIdx.x;
    const bool act = (tid * 8) < kcap;

    union { uint4 u; u16 h[8]; } U;
    if (act) U.u = *reinterpret_cast<const uint4*>(row + tid * 8);
    float v[8];
    float m = -1e30f;
#pragma unroll
    for (int i = 0; i < 8; ++i) {
        int c = tid * 8 + i;
        v[i] = (act && c < n) ? h2f(U.h[i]) : -1e30f;
        m = fmaxf(m, v[i]);
    }
#pragma unroll
    for (int off = 32; off; off >>= 1) m = fmaxf(m, __shfl_xor(m, off));
    __shared__ float redm[4], redsum[4];
    int wave = tid >> 6, lane = tid & 63;
    if (lane == 0) redm[wave] = m;
    __syncthreads();
    m = fmaxf(fmaxf(redm[0], redm[1]), fmaxf(redm[2], redm[3]));
    float M = 32.f * m;

    float sum = 0.f;
#pragma unroll
    for (int i = 0; i < 8; ++i) {
        int c = tid * 8 + i;
        float e = (v[i] > -1e29f) ? __expf(32.f * v[i] - M) : 0.f;
        if (c >= n) e = 0.f;
        v[i] = e;
        sum += e;
    }
#pragma unroll
    for (int off = 32; off; off >>= 1) sum += __shfl_xor(sum, off);
    if (lane == 0) redsum[wave] = sum;
    __syncthreads();
    sum = redsum[0] + redsum[1] + redsum[2] + redsum[3];
    float inv = 1.f / sum;

    if (act) {
        union { uint4 u; u16 h[8]; } O;
#pragma unroll
        for (int i = 0; i < 8; ++i) O.h[i] = f2bf(v[i] * inv);
        *reinterpret_cast<uint4*>(row + tid * 8) = O.u;
    }
}

// ---------- host launcher ----------
extern "C" void kernel_launch(void* const* d_in, const int* in_sizes, int n_in,
                              void* d_out, int out_size, void* d_ws, size_t ws_size,
                              hipStream_t stream) {
    const float* x   = (const float*)d_in[0];   // [4,2048,1024]
    const float* w   = (const float*)d_in[1];   // [3072,1024]
    const float* sqk = (const float*)d_in[2];   // [1024]
    float* out = (float*)d_out;

    const size_t SZ_XB  = (size_t)8192 * 1024 * 2;        // aliased by VT later
    const size_t SZ_WB  = (size_t)3072 * 1024 * 2;
    const size_t SZ_QKV = (size_t)8192 * 3072 * 2;
    const size_t SZ_S   = (size_t)4 * 2048 * 2048 * 2;    // fp16, 4 slots
    const size_t SZ_TR  = (size_t)2048 * 1024 * 2;
    if (ws_size < SZ_XB + SZ_WB + SZ_QKV + SZ_S + SZ_TR) return;

    char* ws = (char*)d_ws;
    u16* xb   = (u16*)ws;  ws += SZ_XB;
    u16* wb   = (u16*)ws;  ws += SZ_WB;
    u16* qkv  = (u16*)ws;  ws += SZ_QKV;
    u16* S    = (u16*)ws;  ws += SZ_S;
    u16* trig = (u16*)ws;
    u16* VT   = xb;   // alias: xb dead after QKV GEMM

    f32_to_bf16<<<2048, 256, 0, stream>>>(x, xb, 8192 * 1024);
    f32_to_bf16<<<768, 256, 0, stream>>>(w, wb, 3072 * 1024);

    // qkv = x @ W^T : [8192,3072], 1536 blocks 1D, XCD-chunked 2D swizzle in-kernel
    gemm_bt<0, u16><<<dim3(1536, 1, 1), 512, 0, stream>>>(
        xb, wb, qkv, 1024, 1024, 1024, 3072, 0, 0, 0);

    trig_table<<<2048, 256, 0, stream>>>(trig);
    rope_norm<<<8192, 256, 0, stream>>>(qkv, sqk, trig);

    transpose_v<<<dim3(32, 64, 4), dim3(32, 8), 0, stream>>>(qkv, VT);

    // S = Q @ K^T, all 4 batches, causal tiles, fp16 output
    gemm_bt<1, _Float16><<<dim3(16, 16, 4), 512, 0, stream>>>(
        qkv, qkv + 1024, (_Float16*)S, 1024, 3072, 3072, 2048,
        (long)2048 * 3072, (long)2048 * 3072, (long)2048 * 2048);

    softmax_inplace<<<dim3(2048, 4), 256, 0, stream>>>(S);

    // out = P @ V, longest-first over row tiles, grid (8, 64)
    gemm_bt<2, float><<<dim3(8, 64, 1), 512, 0, stream>>>(
        S, VT, out, 2048, 2048, 2048, 1024,
        (long)2048 * 2048, (long)1024 * 2048, (long)2048 * 1024);
}